// Round 4
// baseline (706.999 us; speedup 1.0000x reference)
//
#include <hip/hip_runtime.h>
#include <hip/hip_fp16.h>
#include <cstdint>
#include <cstddef>

#define VCUBE 35937      // 33^3
#define LUT_CH 107811    // 3*33^3

typedef float vfloat4 __attribute__((ext_vector_type(4)));

// ---------------- device-scope spin barrier (monotone counters, one per use) ----------------
__device__ __forceinline__ void gbar(unsigned* ctr, int k, unsigned target) {
  __syncthreads();
  if (threadIdx.x == 0) {
    __threadfence();
    atomicAdd(&ctr[k], 1u);
    while (__hip_atomic_load(&ctr[k], __ATOMIC_ACQUIRE, __HIP_MEMORY_SCOPE_AGENT) < target)
      __builtin_amdgcn_s_sleep(2);
    __threadfence();
  }
  __syncthreads();
}

template<int W>
__device__ __forceinline__ void wred2(float& a, float& b) {
#pragma unroll
  for (int d = W / 2; d > 0; d >>= 1) {
    a += __shfl_down(a, d, W);
    b += __shfl_down(b, d, W);
  }
}

// ================= mega kernel: whole CNN + head + ecell, 128*B blocks x 256 =================
__global__ __launch_bounds__(256, 2) void mega_kernel(
    const float* __restrict__ imgs,
    const float* __restrict__ w1, const float* __restrict__ b1, const float* __restrict__ g1, const float* __restrict__ be1,
    const float* __restrict__ w2, const float* __restrict__ b2, const float* __restrict__ g2, const float* __restrict__ be2,
    const float* __restrict__ w3, const float* __restrict__ b3, const float* __restrict__ g3, const float* __restrict__ be3,
    const float* __restrict__ w4, const float* __restrict__ b4, const float* __restrict__ g4, const float* __restrict__ be4,
    const float* __restrict__ w5, const float* __restrict__ b5,
    const float* __restrict__ wgen_w, const float* __restrict__ wgen_b,
    const float* __restrict__ basis_w,
    const float* __restrict__ ada_w, const float* __restrict__ ada_b,
    float* __restrict__ x1, float* __restrict__ x2, float* __restrict__ x3,
    float* __restrict__ x4, float* __restrict__ x5,
    float* __restrict__ gwp, float* __restrict__ vert, float* __restrict__ invt,
    uint8_t* __restrict__ hints, __half* __restrict__ ecell,
    float* __restrict__ stats1, float* __restrict__ stats2,
    float* __restrict__ stats3, float* __restrict__ stats4,
    unsigned* __restrict__ bar, int B) {
  __shared__ float smem[7424];
  const int blk = blockIdx.x;
  const int t = threadIdx.x;
  const unsigned NB = gridDim.x;

  // ---------------- S1: resize(8x bilinear, frac=0.5 exact) + conv1 + lrelu + stats1 ----------------
  {
    const int b = blk >> 7;
    const int oh = blk & 127;
    float* s_w = smem;             // 432
    float* s_in = smem + 432;      // 306
    for (int i = t; i < 432; i += 256) s_w[i] = w1[i];
    const int co = t >> 4, owl = t & 15;
    float s = 0.f, s2 = 0.f;
    const int ihbase = 2 * oh - 1;
    for (int j = 0; j < 8; j++) {         // 8 ow-tiles of 16
      const int ow0 = j * 16;
      const int iwbase = 2 * ow0 - 1;
      __syncthreads();
      for (int i = t; i < 306; i += 256) {
        int x = i % 34; int rest = i / 34; int kh = rest % 3; int ci = rest / 3;
        int ih = ihbase + kh, iw = iwbase + x;
        float v = 0.f;
        if (ih >= 0 && ih < 256 && iw >= 0 && iw < 256) {
          const float* p = imgs + (size_t)(b * 3 + ci) * 2048 * 2048;
          const float* r0 = p + (size_t)(ih * 8 + 3) * 2048 + (iw * 8 + 3);
          const float* r1 = r0 + 2048;
          float a = r0[0], bb = r0[1], c = r1[0], d = r1[1];
          float top = a + 0.5f * (bb - a);
          float bot = c + 0.5f * (d - c);
          v = top + 0.5f * (bot - top);
        }
        s_in[i] = v;
      }
      __syncthreads();
      float acc = b1[co];
      const float* wp = s_w + co * 27;
#pragma unroll
      for (int ci = 0; ci < 3; ci++)
#pragma unroll
        for (int kh = 0; kh < 3; kh++) {
          const float* rp = s_in + (ci * 3 + kh) * 34 + 2 * owl;
          acc = fmaf(rp[0], wp[ci * 9 + kh * 3 + 0], acc);
          acc = fmaf(rp[1], wp[ci * 9 + kh * 3 + 1], acc);
          acc = fmaf(rp[2], wp[ci * 9 + kh * 3 + 2], acc);
        }
      acc = acc >= 0.f ? acc : 0.2f * acc;
      x1[(((size_t)b * 16 + co) * 128 + oh) * 128 + ow0 + owl] = acc;
      s += acc; s2 = fmaf(acc, acc, s2);
    }
    wred2<16>(s, s2);
    if (owl == 0) {
      atomicAdd(&stats1[((b << 4) + co) * 2 + 0], s);
      atomicAdd(&stats1[((b << 4) + co) * 2 + 1], s2);
    }
  }
  gbar(bar, 0, NB);

  // ---------------- S2: conv2 (norm-on-read stats1) + lrelu + stats2 ----------------
  {
    const int b = blk >> 7;
    const int oh = (blk >> 1) & 63;
    const int g0 = (blk & 1) * 4;
    float* sal = smem; float* sbe = smem + 16;
    if (t < 16) {
      float s = stats1[((b << 4) + t) * 2], s2 = stats1[((b << 4) + t) * 2 + 1];
      float mean = s * (1.f / 16384.f);
      float var = s2 * (1.f / 16384.f) - mean * mean;
      float a = g1[t] / sqrtf(var + 1e-5f);
      sal[t] = a; sbe[t] = be1[t] - mean * a;
    }
    __syncthreads();
    float* s_in = smem + 32;   // 6240
    const int ihb = 2 * oh - 1;
    for (int i = t; i < 6240; i += 256) {
      int x = i % 130; int r2 = i / 130; int kh = r2 % 3; int ci = r2 / 3;
      int ih = ihb + kh, iw = x - 1;
      float v = 0.f;
      if (ih >= 0 && ih < 128 && iw >= 0 && iw < 128)
        v = fmaf(x1[((size_t)((b << 4) + ci) * 128 + ih) * 128 + iw], sal[ci], sbe[ci]);
      s_in[i] = v;
    }
    __syncthreads();
    const int ow = t & 63, col = t >> 6;
    for (int gi = 0; gi < 4; gi++) {
      int co = (g0 + gi) * 4 + col;
      float acc = b2[co];
      const float* wp = w2 + (size_t)co * 144;
      for (int ci = 0; ci < 16; ci++) {
        const float* rp = s_in + ci * 390 + 2 * ow;
        const float* wc = wp + ci * 9;
        acc = fmaf(rp[0], wc[0], acc); acc = fmaf(rp[1], wc[1], acc); acc = fmaf(rp[2], wc[2], acc);
        acc = fmaf(rp[130], wc[3], acc); acc = fmaf(rp[131], wc[4], acc); acc = fmaf(rp[132], wc[5], acc);
        acc = fmaf(rp[260], wc[6], acc); acc = fmaf(rp[261], wc[7], acc); acc = fmaf(rp[262], wc[8], acc);
      }
      acc = acc >= 0.f ? acc : 0.2f * acc;
      x2[((size_t)((b << 5) + co) * 64 + oh) * 64 + ow] = acc;
      float s = acc, s2 = acc * acc;
      wred2<64>(s, s2);
      if (ow == 0) {
        atomicAdd(&stats2[((b << 5) + co) * 2 + 0], s);
        atomicAdd(&stats2[((b << 5) + co) * 2 + 1], s2);
      }
    }
  }
  gbar(bar, 1, NB);

  // ---------------- S3: conv3 (norm stats2) + lrelu + stats3 ----------------
  {
    const int b = blk >> 7;
    const int oh = (blk >> 2) & 31;
    const int m = blk & 3;
    float* sal = smem; float* sbe = smem + 32;
    if (t < 32) {
      float s = stats2[((b << 5) + t) * 2], s2 = stats2[((b << 5) + t) * 2 + 1];
      float mean = s * (1.f / 4096.f);
      float var = s2 * (1.f / 4096.f) - mean * mean;
      float a = g2[t] / sqrtf(var + 1e-5f);
      sal[t] = a; sbe[t] = be2[t] - mean * a;
    }
    __syncthreads();
    float* s_in = smem + 64;   // 6336
    const int ihb = 2 * oh - 1;
    for (int i = t; i < 6336; i += 256) {
      int x = i % 66; int r2 = i / 66; int kh = r2 % 3; int ci = r2 / 3;
      int ih = ihb + kh, iw = x - 1;
      float v = 0.f;
      if (ih >= 0 && ih < 64 && iw >= 0 && iw < 64)
        v = fmaf(x2[((size_t)((b << 5) + ci) * 64 + ih) * 64 + iw], sal[ci], sbe[ci]);
      s_in[i] = v;
    }
    __syncthreads();
    const int ow = t & 31, col = t >> 5;
    for (int gi = 0; gi < 2; gi++) {
      int co = (2 * m + gi) * 8 + col;
      float acc = b3[co];
      const float* wp = w3 + (size_t)co * 288;
      for (int ci = 0; ci < 32; ci++) {
        const float* rp = s_in + ci * 198 + 2 * ow;
        const float* wc = wp + ci * 9;
        acc = fmaf(rp[0], wc[0], acc); acc = fmaf(rp[1], wc[1], acc); acc = fmaf(rp[2], wc[2], acc);
        acc = fmaf(rp[66], wc[3], acc); acc = fmaf(rp[67], wc[4], acc); acc = fmaf(rp[68], wc[5], acc);
        acc = fmaf(rp[132], wc[6], acc); acc = fmaf(rp[133], wc[7], acc); acc = fmaf(rp[134], wc[8], acc);
      }
      acc = acc >= 0.f ? acc : 0.2f * acc;
      x3[((size_t)((b << 6) + co) * 32 + oh) * 32 + ow] = acc;
      float s = acc, s2 = acc * acc;
      wred2<32>(s, s2);
      if (ow == 0) {
        atomicAdd(&stats3[((b << 6) + co) * 2 + 0], s);
        atomicAdd(&stats3[((b << 6) + co) * 2 + 1], s2);
      }
    }
  }
  gbar(bar, 2, NB);

  // ---------------- S4: conv4 (norm stats3) + lrelu + stats4 ----------------
  {
    const int b = blk >> 7;
    const int oh = (blk >> 3) & 15;
    const int grp = blk & 7;
    float* sal = smem; float* sbe = smem + 64;
    if (t < 64) {
      float s = stats3[((b << 6) + t) * 2], s2 = stats3[((b << 6) + t) * 2 + 1];
      float mean = s * (1.f / 1024.f);
      float var = s2 * (1.f / 1024.f) - mean * mean;
      float a = g3[t] / sqrtf(var + 1e-5f);
      sal[t] = a; sbe[t] = be3[t] - mean * a;
    }
    __syncthreads();
    float* s_in = smem + 128;  // 6528
    const int ihb = 2 * oh - 1;
    for (int i = t; i < 6528; i += 256) {
      int x = i % 34; int r2 = i / 34; int kh = r2 % 3; int ci = r2 / 3;
      int ih = ihb + kh, iw = x - 1;
      float v = 0.f;
      if (ih >= 0 && ih < 32 && iw >= 0 && iw < 32)
        v = fmaf(x3[((size_t)((b << 6) + ci) * 32 + ih) * 32 + iw], sal[ci], sbe[ci]);
      s_in[i] = v;
    }
    __syncthreads();
    const int ow = t & 15, col = t >> 4;
    int co = grp * 16 + col;
    float acc = b4[co];
    const float* wp = w4 + (size_t)co * 576;
    for (int ci = 0; ci < 64; ci++) {
      const float* rp = s_in + ci * 102 + 2 * ow;
      const float* wc = wp + ci * 9;
      acc = fmaf(rp[0], wc[0], acc); acc = fmaf(rp[1], wc[1], acc); acc = fmaf(rp[2], wc[2], acc);
      acc = fmaf(rp[34], wc[3], acc); acc = fmaf(rp[35], wc[4], acc); acc = fmaf(rp[36], wc[5], acc);
      acc = fmaf(rp[68], wc[6], acc); acc = fmaf(rp[69], wc[7], acc); acc = fmaf(rp[70], wc[8], acc);
    }
    acc = acc >= 0.f ? acc : 0.2f * acc;
    x4[((size_t)((b << 7) + co) * 16 + oh) * 16 + ow] = acc;
    float s = acc, s2 = acc * acc;
    wred2<16>(s, s2);
    if (ow == 0) {
      atomicAdd(&stats4[((b << 7) + co) * 2 + 0], s);
      atomicAdd(&stats4[((b << 7) + co) * 2 + 1], s2);
    }
  }
  gbar(bar, 3, NB);

  // ---------------- S5: conv5 (norm stats4) + lrelu (no stats), split-K x4 ----------------
  {
    const int b = blk >> 7;
    const int oh = (blk >> 4) & 7;
    const int grp = blk & 15;          // 16 groups of 8 co
    float* sal = smem; float* sbe = smem + 128;
    if (t < 128) {
      float s = stats4[((b << 7) + t) * 2], s2 = stats4[((b << 7) + t) * 2 + 1];
      float mean = s * (1.f / 256.f);
      float var = s2 * (1.f / 256.f) - mean * mean;
      float a = g4[t] / sqrtf(var + 1e-5f);
      sal[t] = a; sbe[t] = be4[t] - mean * a;
    }
    __syncthreads();
    float* s_in = smem + 256;      // 6912
    float* part = smem + 7168;     // 256
    const int ihb = 2 * oh - 1;
    for (int i = t; i < 6912; i += 256) {
      int x = i % 18; int r2 = i / 18; int kh = r2 % 3; int ci = r2 / 3;
      int ih = ihb + kh, iw = x - 1;
      float v = 0.f;
      if (ih >= 0 && ih < 16 && iw >= 0 && iw < 16)
        v = fmaf(x4[((size_t)((b << 7) + ci) * 16 + ih) * 16 + iw], sal[ci], sbe[ci]);
      s_in[i] = v;
    }
    __syncthreads();
    const int ow = t & 7, col = (t >> 3) & 7, ks = t >> 6;
    int co = grp * 8 + col;
    float acc = 0.f;
    const float* wp = w5 + (size_t)co * 1152;
    for (int ci = ks * 32; ci < ks * 32 + 32; ci++) {
      const float* rp = s_in + ci * 54 + 2 * ow;
      const float* wc = wp + ci * 9;
      acc = fmaf(rp[0], wc[0], acc); acc = fmaf(rp[1], wc[1], acc); acc = fmaf(rp[2], wc[2], acc);
      acc = fmaf(rp[18], wc[3], acc); acc = fmaf(rp[19], wc[4], acc); acc = fmaf(rp[20], wc[5], acc);
      acc = fmaf(rp[36], wc[6], acc); acc = fmaf(rp[37], wc[7], acc); acc = fmaf(rp[38], wc[8], acc);
    }
    part[t] = acc;
    __syncthreads();
    if (t < 64) {
      float v = part[t] + part[t + 64] + part[t + 128] + part[t + 192];
      int co2 = grp * 8 + (t >> 3);
      int ow2 = t & 7;
      v += b5[co2];
      v = v >= 0.f ? v : 0.2f * v;
      x5[((size_t)((b << 7) + co2) * 8 + oh) * 8 + ow2] = v;
    }
  }
  gbar(bar, 4, NB);

  // ---------------- S6: head (pool + gemvs + softmax/cumsum + inv/hint tables), B blocks ----------------
  if ((blk & 127) == 0) {
    const int b = blk >> 7;
    float* xv = smem;             // 512
    float* logits = smem + 512;   // 96
    float* svp = smem + 608;      // 99
    for (int o = t; o < 512; o += 256) {
      int c = o >> 2, h2 = (o >> 1) & 1, w2 = o & 1;
      const float* p = x5 + ((size_t)(b * 128 + c)) * 64 + h2 * 32 + w2 * 4;
      float s = 0.f;
#pragma unroll
      for (int h = 0; h < 4; h++)
#pragma unroll
        for (int ww = 0; ww < 4; ww++) s += p[h * 8 + ww];
      xv[o] = s * (1.f / 16.f);
    }
    __syncthreads();
    if (t < 96) {
      float s = ada_b[t];
      for (int k = 0; k < 512; k++) s = fmaf(xv[k], ada_w[k * 96 + t], s);
      logits[t] = s;
    } else if (t < 99) {
      int j = t - 96;
      float s = wgen_b[j];
      for (int k = 0; k < 512; k++) s = fmaf(xv[k], wgen_w[k * 3 + j], s);
      gwp[b * 3 + j] = s;
    }
    __syncthreads();
    if (t < 3) {
      const float* l = logits + t * 32;
      float m = l[0];
#pragma unroll
      for (int i = 1; i < 32; i++) m = fmaxf(m, l[i]);
      float e[32]; float sum = 0.f;
#pragma unroll
      for (int i = 0; i < 32; i++) { e[i] = expf(l[i] - m); sum += e[i]; }
      float inv = 1.0f / sum;
      float* vp = vert + b * 99 + t * 33;
      svp[t * 33] = 0.f; vp[0] = 0.f;
      float cum = 0.f;
#pragma unroll
      for (int i = 0; i < 32; i++) {
        cum = fmaf(e[i], inv, cum);
        svp[t * 33 + i + 1] = cum; vp[i + 1] = cum;
      }
    }
    __syncthreads();
    if (t < 96) {
      int c = t >> 5, i = t & 31;
      float d = svp[c * 33 + i + 1] - svp[c * 33 + i];
      invt[b * 96 + t] = 1.0f / fmaxf(d, 1e-10f);
    }
    for (int e = t; e < 3072; e += 256) {
      int c = e >> 10; int bin = e & 1023;
      float q0 = (float)bin * (1.f / 1024.f);
      const float* v = svp + c * 33;
      int lo = 0, hi = 33;
      while (lo < hi) { int mid = (lo + hi) >> 1; if (v[mid] <= q0) lo = mid + 1; else hi = mid; }
      int idx = lo - 1; if (idx > 31) idx = 31;
      hints[b * 3072 + e] = (uint8_t)idx;
    }
  }
  gbar(bar, 5, NB);

  // ---------------- S7: ecell build (packed: h[(dg*2+dr)*2+db]) ----------------
  {
    int total = B * 98304;
    for (int it = blk * 256 + t; it < total; it += (int)NB * 256) {
      int cc = it % 3; int cell = it / 3;
      int r = cell & 31, g = (cell >> 5) & 31, bl = (cell >> 10) & 31, b = cell >> 15;
      float w0 = gwp[b * 3 + 0], w1c = gwp[b * 3 + 1], w2c = gwp[b * 3 + 2];
      union { __half h[8]; uint4 u; } pk;
#pragma unroll
      for (int dg = 0; dg < 2; dg++)
#pragma unroll
        for (int dr = 0; dr < 2; dr++)
#pragma unroll
          for (int db = 0; db < 2; db++) {
            int flat = cc * VCUBE + ((bl + db) * 33 + (g + dg)) * 33 + (r + dr);
            float val = w0 * basis_w[flat] + w1c * basis_w[LUT_CH + flat] + w2c * basis_w[2 * LUT_CH + flat];
            pk.h[(dg * 2 + dr) * 2 + db] = __float2half(val);
          }
      *(uint4*)((uint16_t*)ecell + (size_t)cell * 32 + cc * 8) = pk.u;
    }
  }
}

// ================= transform: 12 loads in flight, packed-fp16 lerps =================
__global__ __launch_bounds__(256, 2) void transform_kernel(const float* __restrict__ imgs,
    const __half* __restrict__ ecell, const float* __restrict__ vert,
    const float* __restrict__ invtab, const unsigned int* __restrict__ hintw,
    float* __restrict__ out, int B) {
  const size_t N = 2048u * 2048u;
  __shared__ float sv[99];
  __shared__ float sinv[96];
  __shared__ unsigned int shint_w[768];
  int b = blockIdx.x % B;          // XCD parity: even blocks -> b=0 (blk%8 XCD round-robin)
  int pblk = blockIdx.x / B;
  int t = threadIdx.x;
  if (t < 99) sv[t] = vert[b * 99 + t];
  if (t < 96) sinv[t] = invtab[b * 96 + t];
  for (int i = t; i < 768; i += 256) shint_w[i] = hintw[b * 768 + i];
  __syncthreads();
  const uint8_t* shint = (const uint8_t*)shint_w;
  size_t pix = ((size_t)pblk * 256 + t) * 4;
  const float* ip = imgs + (size_t)b * 3 * N;
  float* op = out + (size_t)b * 3 * N;
  const __half* ec = ecell + (size_t)b * 1048576;
  vfloat4 r  = __builtin_nontemporal_load((const vfloat4*)(ip + pix));
  vfloat4 g  = __builtin_nontemporal_load((const vfloat4*)(ip + N + pix));
  vfloat4 bb = __builtin_nontemporal_load((const vfloat4*)(ip + 2 * N + pix));
  float R[4] = {r.x, r.y, r.z, r.w};
  float G[4] = {g.x, g.y, g.z, g.w};
  float Bb[4] = {bb.x, bb.y, bb.z, bb.w};
  int cofs[4]; float fRa[4], fGa[4], fBa[4];
#pragma unroll
  for (int p = 0; p < 4; p++) {
    float q[3] = { fminf(fmaxf(R[p], 0.f), 1.f), fminf(fmaxf(G[p], 0.f), 1.f), fminf(fmaxf(Bb[p], 0.f), 1.f) };
    int id[3]; float fr[3];
#pragma unroll
    for (int c = 0; c < 3; c++) {
      float qc = q[c];
      int bin = (int)(qc * 1024.f); bin = bin > 1023 ? 1023 : bin;
      int idx = shint[(c << 10) + bin];
      const float* v = sv + c * 33;
      idx += (idx < 31 && v[idx + 1] <= qc) ? 1 : 0;
      idx += (idx < 31 && v[idx + 1] <= qc) ? 1 : 0;
      float f = (qc - v[idx]) * sinv[(c << 5) + idx];
      fr[c] = fminf(fmaxf(f, 0.f), 1.f);
      id[c] = idx;
    }
    cofs[p] = (((id[2] << 5) + id[1]) << 5) + id[0];
    fRa[p] = fr[0]; fGa[p] = fr[1]; fBa[p] = fr[2];
  }
  uint4 u[12];
#pragma unroll
  for (int p = 0; p < 4; p++) {
    const __half* cell = ec + (size_t)cofs[p] * 32;
    u[p * 3 + 0] = *(const uint4*)(cell);
    u[p * 3 + 1] = *(const uint4*)(cell + 8);
    u[p * 3 + 2] = *(const uint4*)(cell + 16);
  }
  float oc[3][4];
#pragma unroll
  for (int p = 0; p < 4; p++) {
    __half2 fR2 = __float2half2_rn(fRa[p]);
    __half2 fG2 = __float2half2_rn(fGa[p]);
    float fB = fBa[p];
#pragma unroll
    for (int cc = 0; cc < 3; cc++) {
      union { uint4 v; __half2 h2[4]; } m; m.v = u[p * 3 + cc];
      __half2 a  = __hfma2(fR2, __hsub2(m.h2[1], m.h2[0]), m.h2[0]);
      __half2 b2 = __hfma2(fR2, __hsub2(m.h2[3], m.h2[2]), m.h2[2]);
      __half2 cg = __hfma2(fG2, __hsub2(b2, a), a);
      float lo = __low2float(cg), hi = __high2float(cg);
      oc[cc][p] = fmaf(fB, hi - lo, lo);
    }
  }
  vfloat4 o0 = {oc[0][0], oc[0][1], oc[0][2], oc[0][3]};
  vfloat4 o1 = {oc[1][0], oc[1][1], oc[1][2], oc[1][3]};
  vfloat4 o2 = {oc[2][0], oc[2][1], oc[2][2], oc[2][3]};
  __builtin_nontemporal_store(o0, (vfloat4*)(op + pix));
  __builtin_nontemporal_store(o1, (vfloat4*)(op + N + pix));
  __builtin_nontemporal_store(o2, (vfloat4*)(op + 2 * N + pix));
}

// ================= launch: 3 graph nodes =================
extern "C" void kernel_launch(void* const* d_in, const int* in_sizes, int n_in,
                              void* d_out, int out_size, void* d_ws, size_t ws_size,
                              hipStream_t stream) {
  const float* imgs = (const float*)d_in[0];
  const float* w1 = (const float*)d_in[1];  const float* b1 = (const float*)d_in[2];
  const float* g1 = (const float*)d_in[3];  const float* be1 = (const float*)d_in[4];
  const float* w2 = (const float*)d_in[5];  const float* b2 = (const float*)d_in[6];
  const float* g2 = (const float*)d_in[7];  const float* be2 = (const float*)d_in[8];
  const float* w3 = (const float*)d_in[9];  const float* b3 = (const float*)d_in[10];
  const float* g3 = (const float*)d_in[11]; const float* be3 = (const float*)d_in[12];
  const float* w4 = (const float*)d_in[13]; const float* b4 = (const float*)d_in[14];
  const float* g4 = (const float*)d_in[15]; const float* be4 = (const float*)d_in[16];
  const float* w5 = (const float*)d_in[17]; const float* b5 = (const float*)d_in[18];
  const float* wgen_w  = (const float*)d_in[19];
  const float* wgen_b  = (const float*)d_in[20];
  const float* basis_w = (const float*)d_in[21];
  const float* ada_w   = (const float*)d_in[22];
  const float* ada_b   = (const float*)d_in[23];
  float* out = (float*)d_out;

  const int B = in_sizes[0] / (3 * 2048 * 2048);

  char* wsb = (char*)d_ws;
  __half* ecell = (__half*)wsb;                       // B*2 MB, aliases x1..x5 (dead by then)
  float* x1 = (float*)wsb;
  float* x2 = x1 + (size_t)B * 262144;
  float* x3 = x2 + (size_t)B * 131072;
  float* x4 = x3 + (size_t)B * 65536;
  float* x5 = x4 + (size_t)B * 32768;
  size_t A_bytes = (size_t)B * 2097152;
  float* gwp  = (float*)(wsb + A_bytes);              // B*4
  float* vert = gwp + (size_t)B * 4;                  // B*99
  float* invt = vert + (size_t)B * 99;                // B*96
  uint8_t* hints = (uint8_t*)(invt + (size_t)B * 96); // B*3072 bytes
  float* stats = (float*)(hints + (size_t)B * 3072);  // B*480 floats (zeroed)
  float* stats1 = stats;
  float* stats2 = stats1 + (size_t)B * 32;
  float* stats3 = stats2 + (size_t)B * 64;
  float* stats4 = stats3 + (size_t)B * 128;
  unsigned* bar = (unsigned*)(stats + (size_t)B * 480); // 8 uints (zeroed)

  size_t zero_bytes = (size_t)B * 480 * 4 + 32;
  (void)hipMemsetAsync(stats, 0, zero_bytes, stream);

  mega_kernel<<<dim3(128 * B), 256, 0, stream>>>(
      imgs, w1, b1, g1, be1, w2, b2, g2, be2, w3, b3, g3, be3, w4, b4, g4, be4,
      w5, b5, wgen_w, wgen_b, basis_w, ada_w, ada_b,
      x1, x2, x3, x4, x5, gwp, vert, invt, hints, ecell,
      stats1, stats2, stats3, stats4, bar, B);

  transform_kernel<<<dim3(B * 4096), 256, 0, stream>>>(imgs, ecell, vert, invt,
                                                       (const unsigned int*)hints, out, B);
}